// Round 11
// baseline (43.396 us; speedup 1.0000x reference)
//
#include <hip/hip_runtime.h>
#include <hip/hip_bf16.h>

#define B_ 8
#define W_ 128
#define K_ 2048
#define D_ 256
#define WX 144            // padded w-dim: 128 x-cols + E1-col(128) + 15 zero cols
#define NC 256            // K/8 j-chunks

typedef __attribute__((ext_vector_type(8))) short bf16x8;
typedef __attribute__((ext_vector_type(4))) float f32x4;

static __device__ __forceinline__ short f2bf(float f) {
    unsigned int u = __float_as_uint(f);
    unsigned int r = (u + 0x7FFFu + ((u >> 16) & 1u)) >> 16;
    return (short)r;
}

// ---------- k_w2v: w2v[w] = sum_d W_lin[W+w][d] * a[d]  (128 blocks x 1 wave)
__global__ void k_w2v(const float* __restrict__ W_lin, const float* __restrict__ a,
                      float* __restrict__ w2v) {
    int w = blockIdx.x, l = threadIdx.x;
    float4 rv = ((const float4*)(W_lin + (size_t)(W_ + w) * D_))[l];
    float4 av = ((const float4*)a)[l];
    float acc = rv.x * av.x + rv.y * av.y + rv.z * av.z + rv.w * av.w;
    for (int m = 1; m < 64; m <<= 1) acc += __shfl_xor(acc, m);
    if (l == 0) w2v[w] = acc;
}

// ---------- k_pe: heterogeneous grid (768 blocks x 512 thr)
// blocks 0..511  : prep -> u2 reduce, E1=exp(u2), xbt = bf16(x*E1) blocked (+E1 col)
// blocks 512..767: e2   -> E2 = bf16(exp(bias-rowmax)), 8 rows/block, e2t[c][i][e]
__global__ __launch_bounds__(512) void k_pe(const float* __restrict__ x,
        const float* __restrict__ w2v, const float* __restrict__ bias,
        short* __restrict__ xbt, short* __restrict__ e2t) {
    __shared__ float sc[696];
    int tid = threadIdx.x;
    int wid = tid >> 6;
    int lane = tid & 63;

    if (blockIdx.x < 512) {
        // ---- prep: this block owns 32 k-cols ----
        if (tid < W_) sc[tid] = w2v[tid];          // ws
        __syncthreads();
        int q = tid & 31, cw = tid >> 5;           // cw 0..15, 8 w each
        int bk0 = blockIdx.x * 32;
        int b = bk0 >> 11;
        int k = (bk0 & (K_ - 1)) + q;
        const float* xp = x + ((size_t)b * W_ + cw * 8) * K_ + k;
        float xv[8];
        float acc = 0.f;
#pragma unroll
        for (int w = 0; w < 8; ++w) {
            xv[w] = xp[(size_t)w * K_];
            acc += xv[w] * sc[cw * 8 + w];
        }
        sc[128 + cw * 33 + q] = acc;               // red[16][33]
        __syncthreads();
        if (tid < 32) {
            float s = 0.f;
#pragma unroll
            for (int cc = 0; cc < 16; ++cc) s += sc[128 + cc * 33 + tid];
            sc[656 + tid] = __expf(s);             // e1s; |u2| small, shift-invariant
        }
        __syncthreads();
        float e1q = sc[656 + q];
        short* xo = xbt + (((size_t)b * NC + (k >> 3)) * WX + cw * 8) * 8 + (k & 7);
#pragma unroll
        for (int w = 0; w < 8; ++w) xo[w * 8] = f2bf(xv[w] * e1q);
        if (tid < 32) {   // E1 column (w=128)
            int kk = (bk0 & (K_ - 1)) + tid;
            xbt[(((size_t)b * NC + (kk >> 3)) * WX + 128) * 8 + (kk & 7)] = f2bf(sc[656 + tid]);
        }
        if (tid >= 64 && tid < 124) {   // zero cols 129..143, this block's 4 c-chunks
            int id = tid - 64;
            int cl = id / 15, wz = 129 + id % 15;
            int c = ((bk0 & (K_ - 1)) >> 3) + cl;
            bf16x8 z = {0, 0, 0, 0, 0, 0, 0, 0};
            *(bf16x8*)(xbt + (((size_t)b * NC + c) * WX + wz) * 8) = z;
        }
    } else {
        // ---- e2: 8 rows per block (256 blocks), 64-B write runs ----
        int i0e = (blockIdx.x - 512) * 8;
        {
            // pass 1: rowmax, one wave per row (fully coalesced)
            const float4* bp = (const float4*)(bias + (size_t)(i0e + wid) * K_);
            float m = -1e30f;
#pragma unroll
            for (int s = 0; s < 8; ++s) {
                float4 v = bp[lane + s * 64];
                m = fmaxf(m, fmaxf(fmaxf(v.x, v.y), fmaxf(v.z, v.w)));
            }
#pragma unroll
            for (int mm = 1; mm < 64; mm <<= 1) m = fmaxf(m, __shfl_xor(m, mm));
            if (lane == 0) sc[wid] = m;
        }
        __syncthreads();
        {
            // pass 2: exp + pack; i inner across threads -> 64-B contiguous runs
            int ilr = tid & 7, cg = tid >> 3;      // cg 0..63, 4 c-chunks each
            float mb = sc[ilr];
            int i = i0e + ilr;
            const float4* brow = (const float4*)(bias + (size_t)i * K_);
#pragma unroll
            for (int it = 0; it < 4; ++it) {
                int c = cg * 4 + it;
                float4 v0 = brow[c * 2];
                float4 v1 = brow[c * 2 + 1];
                bf16x8 o;
                o[0] = f2bf(__expf(v0.x - mb)); o[1] = f2bf(__expf(v0.y - mb));
                o[2] = f2bf(__expf(v0.z - mb)); o[3] = f2bf(__expf(v0.w - mb));
                o[4] = f2bf(__expf(v1.x - mb)); o[5] = f2bf(__expf(v1.y - mb));
                o[6] = f2bf(__expf(v1.z - mb)); o[7] = f2bf(__expf(v1.w - mb));
                *(bf16x8*)(e2t + ((size_t)c * K_ + i) * 8) = o;
            }
        }
    }
}

// ---------- k_gemm: D[i,wcol] = sum_j E2[i,j]*X'[wcol,j]; col 128 = l.
// grid 512: b = blk&7 (XCD-local xbt slice), i0 = (blk>>3)*32 (32 rows).
// 8 waves = 2 n-halves (nh: n 0..4 / 5..8, nh1 pads 5th to dup of n=8)
//         x 4 j-slices (js: 512 j each).
// acc = 2m x 5n = 40 VGPR; depth-2 X/Y prefetch set = 28 VGPR -> ~112 total,
// under the 128-VGPR cliff -> 4 waves/SIMD WITH pipelining.
struct SetH { bf16x8 A0, A1, B0, B1, B2, B3, B4; };

#define MF(a_, b_, c_) __builtin_amdgcn_mfma_f32_16x16x32_bf16(a_, b_, c_, 0, 0, 0)

#define FETCHH(S, c_) do {                                         \
    const short* _e = eA + (size_t)(c_) * (K_ * 8);                \
    const short* _x = xB + (size_t)(c_) * (WX * 8);                \
    S.A0 = *(const bf16x8*)(_e);                                   \
    S.A1 = *(const bf16x8*)(_e + 128);                             \
    S.B0 = *(const bf16x8*)(_x + no0);                             \
    S.B1 = *(const bf16x8*)(_x + no1);                             \
    S.B2 = *(const bf16x8*)(_x + no2);                             \
    S.B3 = *(const bf16x8*)(_x + no3);                             \
    S.B4 = *(const bf16x8*)(_x + no4);                             \
} while (0)

#define CONSUMEH(S) do {                                           \
    a00 = MF(S.A0, S.B0, a00); a10 = MF(S.A1, S.B0, a10);          \
    a01 = MF(S.A0, S.B1, a01); a11 = MF(S.A1, S.B1, a11);          \
    a02 = MF(S.A0, S.B2, a02); a12 = MF(S.A1, S.B2, a12);          \
    a03 = MF(S.A0, S.B3, a03); a13 = MF(S.A1, S.B3, a13);          \
    a04 = MF(S.A0, S.B4, a04); a14 = MF(S.A1, S.B4, a14);          \
} while (0)

__global__ __launch_bounds__(512, 4) void k_gemm(const short* __restrict__ e2t,
        const short* __restrict__ xbt, float* __restrict__ out) {
    __shared__ f32x4 slots[4][10][64];   // 40 KB; aliased as [144][36] f32 epilogue
    int blk  = blockIdx.x;
    int b    = blk & 7;                  // XCD round-robin -> same b per XCD
    int i0   = (blk >> 3) * 32;
    int tid  = threadIdx.x;
    int wid  = tid >> 6;
    int lane = tid & 63;
    int il   = lane & 15;
    int kg   = lane >> 4;
    int nh   = wid & 1;                  // n-half
    int js   = wid >> 1;                 // j-slice (512 j)

    // n-tile short-offsets; nh1's 5th pads to n=8 (dup, L1-hit, discarded)
    int nb = nh * 5;
    int no0 = (nb + 0 > 8 ? 8 : nb + 0) * 128;
    int no1 = (nb + 1 > 8 ? 8 : nb + 1) * 128;
    int no2 = (nb + 2 > 8 ? 8 : nb + 2) * 128;
    int no3 = (nb + 3 > 8 ? 8 : nb + 3) * 128;
    int no4 = (nb + 4 > 8 ? 8 : nb + 4) * 128;

    const short* eA = e2t + ((size_t)kg * K_ + i0 + il) * 8;
    const short* xB = xbt + (((size_t)b * NC + kg) * WX + il) * 8;

    f32x4 a00{0,0,0,0}, a01{0,0,0,0}, a02{0,0,0,0}, a03{0,0,0,0}, a04{0,0,0,0};
    f32x4 a10{0,0,0,0}, a11{0,0,0,0}, a12{0,0,0,0}, a13{0,0,0,0}, a14{0,0,0,0};

    int c0 = js * 64;                    // 64 chunks = 512 j; 16 k-steps of 4 chunks
    SetH X, Y;
    FETCHH(X, c0);
    for (int s = 0; s < 16; s += 2) {
        FETCHH(Y, c0 + (s + 1) * 4);
        CONSUMEH(X);
        if (s + 2 < 16) FETCHH(X, c0 + (s + 2) * 4);
        CONSUMEH(Y);
    }

#define DUMPH(slot) do {                                            \
    slots[slot][0][lane] = a00; slots[slot][1][lane] = a01;         \
    slots[slot][2][lane] = a02; slots[slot][3][lane] = a03;         \
    slots[slot][4][lane] = a04; slots[slot][5][lane] = a10;         \
    slots[slot][6][lane] = a11; slots[slot][7][lane] = a12;         \
    slots[slot][8][lane] = a13; slots[slot][9][lane] = a14; } while (0)
#define GATHH(slot) do {                                            \
    a00 += slots[slot][0][lane]; a01 += slots[slot][1][lane];       \
    a02 += slots[slot][2][lane]; a03 += slots[slot][3][lane];       \
    a04 += slots[slot][4][lane]; a10 += slots[slot][5][lane];       \
    a11 += slots[slot][6][lane]; a12 += slots[slot][7][lane];       \
    a13 += slots[slot][8][lane]; a14 += slots[slot][9][lane]; } while (0)

    // tree over j-slices within each nh: 4 -> 2 -> 1
    if (js >= 2) DUMPH(nh * 2 + (js & 1));
    __syncthreads();
    if (js < 2) GATHH(nh * 2 + js);
    __syncthreads();
    if (js == 1) DUMPH(nh);
    __syncthreads();
    if (js == 0) GATHH(nh);
    __syncthreads();
    if (js == 0) {
        float* arr = (float*)slots;      // [col 144][36 padded rows]
#define WRH(q_, aA_, aB_) do { int n_ = nb + q_; if (n_ > 8) n_ = 8;        \
        *(f32x4*)(arr + (n_ * 16 + il) * 36 + kg * 4)      = aA_;           \
        *(f32x4*)(arr + (n_ * 16 + il) * 36 + 16 + kg * 4) = aB_; } while (0)
        WRH(0, a00, a10); WRH(1, a01, a11); WRH(2, a02, a12);
        WRH(3, a03, a13); WRH(4, a04, a14);
    }
    __syncthreads();

    // epilogue: col = tid>>2 (0..127), rows rs..rs+7; l in col 128
    {
        float* arr = (float*)slots;
        int col = tid >> 2;
        int rs  = (tid & 3) * 8;
        f32x4 n0 = *(f32x4*)(arr + col * 36 + rs);
        f32x4 n1 = *(f32x4*)(arr + col * 36 + rs + 4);
        f32x4 l0 = *(f32x4*)(arr + 128 * 36 + rs);
        f32x4 l1 = *(f32x4*)(arr + 128 * 36 + rs + 4);
        float4 o0, o1;
        o0.x = 1.f / (1.f + __expf(-n0[0] / l0[0]));
        o0.y = 1.f / (1.f + __expf(-n0[1] / l0[1]));
        o0.z = 1.f / (1.f + __expf(-n0[2] / l0[2]));
        o0.w = 1.f / (1.f + __expf(-n0[3] / l0[3]));
        o1.x = 1.f / (1.f + __expf(-n1[0] / l1[0]));
        o1.y = 1.f / (1.f + __expf(-n1[1] / l1[1]));
        o1.z = 1.f / (1.f + __expf(-n1[2] / l1[2]));
        o1.w = 1.f / (1.f + __expf(-n1[3] / l1[3]));
        float* op = out + ((size_t)b * W_ + col) * K_ + i0 + rs;
        *(float4*)op = o0;
        *(float4*)(op + 4) = o1;
    }
}

extern "C" void kernel_launch(void* const* d_in, const int* in_sizes, int n_in,
                              void* d_out, int out_size, void* d_ws, size_t ws_size,
                              hipStream_t stream) {
    const float* x     = (const float*)d_in[0];
    const float* W_lin = (const float*)d_in[1];
    // d_in[2] = b_lin: constant along softmax axis -> cancels, unused
    const float* a     = (const float*)d_in[3];
    const float* bias  = (const float*)d_in[4];
    float* out = (float*)d_out;

    float* w2v = (float*)d_ws;                    // 128 f32
    short* xbt = (short*)(w2v + 128);             // 8*256*144*8 bf16 = 4.72 MB
    short* e2t = xbt + (size_t)B_ * NC * WX * 8;  // 256*2048*8 bf16 = 8 MB

    k_w2v <<<128, 64, 0, stream>>>(W_lin, a, w2v);
    k_pe  <<<768, 512, 0, stream>>>(x, w2v, bias, xbt, e2t);
    k_gemm<<<512, 512, 0, stream>>>(e2t, xbt, out);
}